// Round 7
// baseline (487.551 us; speedup 1.0000x reference)
//
#include <hip/hip_runtime.h>

// MiniSelfAttention: B=8, T=2048, D=1024, fp32 in/out, fp16 MFMA internally.
// R14 = R13 with ctx & proj moved from gemmB (256^2, 128KB LDS, hard 1
// block/CU: 240 regs/wave + LDS both cap it) to gemmA (128^2, 32KB, 4
// blocks/CU). Mechanism: this session's strongest within-run result is that
// the 2-phase loop collapses at 1 block/CU (QKV 204us @256^2/1-per-CU vs
// 136us @128^2/4-per-CU) -- the per-K-tile vmcnt(0)+barrier drain idles the
// CU unless co-resident blocks cover it. ctx(256 blk) and proj(256 blk)
// were the remaining 1/CU ops. S keeps gemmB (512 blk = 2/CU).
// gemmA gets back compile-time EPI 0/1 epilogues (block-uniform).
//
// ws layout (MB):
//   [0,6)    WqkvT = WqT|WkT|WvT contiguous (fp16 [3072][1024])
//   [6,8)    WpT fp16
//   [8,40)   q fp16 [8][2048][1024]   (later overwritten by ctx)
//   [40,72)  k fp16
//   [72,104) vT fp16 [8][1024][2048]
//   [104,136) x16 fp16 (dead after QKV), overlaid by:
//   [104,168) S fp16 [8][2048][2048]  (softmaxed in place -> P)

typedef _Float16 half_t;
typedef _Float16 half4 __attribute__((ext_vector_type(4)));
typedef _Float16 half8 __attribute__((ext_vector_type(8)));
typedef float floatx4 __attribute__((ext_vector_type(4)));

// async global->LDS, 16B per lane; LDS dest = wave-uniform base + lane*16
#define GLD16(gp, lp)                                                          \
    __builtin_amdgcn_global_load_lds(                                          \
        (const __attribute__((address_space(1))) void*)(gp),                   \
        (__attribute__((address_space(3))) void*)(lp), 16, 0, 0)

#define WAIT_VM0()  asm volatile("s_waitcnt vmcnt(0)" ::: "memory")
#define BARRIER()   do { asm volatile("" ::: "memory");                        \
                         __builtin_amdgcn_s_barrier();                         \
                         asm volatile("" ::: "memory"); } while (0)

// ---------------------------------------------------------------------------
// Kernel A: fp16 NT GEMM, 128x128 tile, BK=32, 256 thr (4 waves 64x64),
// 32 KB double-buffered LDS (4 blocks/CU), XOR-swizzled chunks.
// EPI: 0 = fp16 C; 1 = fp32 C + bias; 2 = QKV routed (q*1/32, k, vT via
// LDS-transpose). All routing branches block-uniform.
// ---------------------------------------------------------------------------
template<int EPI>
__global__ __launch_bounds__(256, 4)
void gemmA(const half_t* __restrict__ A, const half_t* __restrict__ B,
           void* __restrict__ Cv, void* __restrict__ C2, void* __restrict__ C3,
           const float* __restrict__ bias, int K, int lda, int ldb, int ldc,
           long long bsA, long long bsB, long long bsC)
{
    __shared__ half_t smem[16384];       // 32 KB: As(16KB) | Bs(16KB)
    half_t* const As = smem;             // reused whole as vt[128][128] in epi
    half_t* const Bs = smem + 8192;

    const int tid  = threadIdx.x;
    const int lane = tid & 63;
    const int w    = tid >> 6;           // 0..3
    const int wm   = w >> 1;             // wave grid 2 (rows) x 2 (cols)
    const int wn   = w & 1;

    // bijective XCD remap (m204) of flattened block id
    int bx = blockIdx.x, by = blockIdx.y, bz = blockIdx.z;
    {
        const int gx = gridDim.x, gy = gridDim.y;
        const int nwg = gx * gy * (int)gridDim.z;
        int lid = (bz * gy + by) * gx + bx;
        const int qq = nwg >> 3, rr = nwg & 7;
        const int xcd = lid & 7, off = lid >> 3;
        lid = (xcd < rr ? xcd * (qq + 1) : rr * (qq + 1) + (xcd - rr) * qq) + off;
        bx = lid % gx; lid /= gx;
        by = lid % gy; bz = lid / gy;
    }
    const long long z = bz;
    const int rowBase = by * 128;
    const int colBase = bx * 128;

    // staging: 256 rows of 64B = 16 groups of 16 rows, 4 groups per wave.
    // SWIZZLE: lane stages global chunk (lane&3)^((lane>>3)&3) of its row,
    // so LDS slot (r, sc) holds global chunk sc^((r>>1)&3).
    const int lrow = lane >> 2;                              // 0..15
    const int scol = (((lane & 3) ^ ((lane >> 3) & 3))) * 8; // swizzled chunk

    const half_t* gptr[4];
    int  lofs[4];
    bool isA[4];
    #pragma unroll
    for (int j = 0; j < 4; ++j) {
        const int g = w * 4 + j;          // 0..15
        if (g < 8) {
            gptr[j] = A + z * bsA + (long long)(rowBase + g * 16 + lrow) * lda + scol;
            lofs[j] = g * 16 * 32;
            isA[j]  = true;
        } else {
            gptr[j] = B + z * bsB + (long long)(colBase + (g - 8) * 16 + lrow) * ldb + scol;
            lofs[j] = (g - 8) * 16 * 32;
            isA[j]  = false;
        }
    }

    floatx4 acc[4][4];
    #pragma unroll
    for (int m = 0; m < 4; ++m)
        #pragma unroll
        for (int n = 0; n < 4; ++n)
            #pragma unroll
            for (int j = 0; j < 4; ++j) acc[m][n][j] = 0.0f;

    const int fr  = lane & 15;
    const int fks = (((lane >> 4) ^ ((lane >> 1) & 3))) * 8;
    const int nIter = K >> 5;

    #pragma unroll
    for (int j = 0; j < 4; ++j)
        GLD16(gptr[j], isA[j] ? &As[lofs[j]] : &Bs[lofs[j]]);
    WAIT_VM0();
    BARRIER();

    for (int it = 0; it < nIter; ++it) {
        const int cur = (it & 1) * 4096;
        const int nxt = 4096 - cur;
        if (it + 1 < nIter) {
            const int kk = (it + 1) << 5;
            #pragma unroll
            for (int j = 0; j < 4; ++j)
                GLD16(gptr[j] + kk, isA[j] ? &As[nxt + lofs[j]] : &Bs[nxt + lofs[j]]);
        }

        half8 af[4], bf[4];
        #pragma unroll
        for (int m = 0; m < 4; ++m)
            af[m] = *(const half8*)&As[cur + (wm * 64 + m * 16 + fr) * 32 + fks];
        #pragma unroll
        for (int n = 0; n < 4; ++n)
            bf[n] = *(const half8*)&Bs[cur + (wn * 64 + n * 16 + fr) * 32 + fks];
        #pragma unroll
        for (int m = 0; m < 4; ++m)
            #pragma unroll
            for (int n = 0; n < 4; ++n)
                acc[m][n] = __builtin_amdgcn_mfma_f32_16x16x32_f16(af[m], bf[n], acc[m][n], 0, 0, 0);

        WAIT_VM0();
        BARRIER();
    }

    // epilogue: C/D layout col=lane&15, row=(lane>>4)*4+reg (gfx950-verified)
    const int ecol = lane & 15;
    const int q4   = (lane >> 4) * 4;
    if (EPI == 0) {
        #pragma unroll
        for (int m = 0; m < 4; ++m)
            #pragma unroll
            for (int n = 0; n < 4; ++n) {
                const int gcol = colBase + wn * 64 + n * 16 + ecol;
                #pragma unroll
                for (int r = 0; r < 4; ++r) {
                    const int grow = rowBase + wm * 64 + m * 16 + q4 + r;
                    ((half_t*)Cv)[z * bsC + (long long)grow * ldc + gcol] =
                        (half_t)acc[m][n][r];
                }
            }
    } else if (EPI == 1) {
        #pragma unroll
        for (int m = 0; m < 4; ++m)
            #pragma unroll
            for (int n = 0; n < 4; ++n) {
                const int gcol = colBase + wn * 64 + n * 16 + ecol;
                #pragma unroll
                for (int r = 0; r < 4; ++r) {
                    const int grow = rowBase + wm * 64 + m * 16 + q4 + r;
                    ((float*)Cv)[(long long)grow * ldc + gcol] =
                        acc[m][n][r] + bias[gcol];
                }
            }
    } else {
        // QKV routing, all branches BLOCK-UNIFORM (from colBase).
        const int mat = colBase >> 10;      // 0=q, 1=k, 2=v
        if (mat < 2) {
            half_t* const Cq = (mat == 0) ? (half_t*)Cv : (half_t*)C2;
            const float sc = (mat == 0) ? 0.03125f : 1.0f;
            const int cb = colBase & 1023;
            #pragma unroll
            for (int m = 0; m < 4; ++m)
                #pragma unroll
                for (int n = 0; n < 4; ++n) {
                    const int c = cb + wn * 64 + n * 16 + ecol;
                    #pragma unroll
                    for (int r = 0; r < 4; ++r) {
                        const int grow = rowBase + wm * 64 + m * 16 + q4 + r;
                        Cq[(long long)grow * 1024 + c] = (half_t)(acc[m][n][r] * sc);
                    }
                }
        } else {
            // vT[b][c][t] via LDS transpose (smem dead after final barrier).
            // halves addr = c*128 + 8*((t>>3)^(c&15)) + (t&7); half4 writes.
            #pragma unroll
            for (int m = 0; m < 4; ++m) {
                const int t0  = wm * 64 + m * 16 + q4;   // 4-aligned
                const int tch = t0 >> 3, tof = t0 & 7;
                #pragma unroll
                for (int n = 0; n < 4; ++n) {
                    const int cl = wn * 64 + n * 16 + ecol;
                    half4 hv;
                    #pragma unroll
                    for (int r = 0; r < 4; ++r) hv[r] = (half_t)acc[m][n][r];
                    *(half4*)&smem[cl * 128 + 8 * (tch ^ (cl & 15)) + tof] = hv;
                }
            }
            BARRIER();
            // stream out coalesced half8 rows of vT.
            const long long bb = rowBase >> 11;          // batch (uniform)
            const int tb = rowBase & 2047;
            const int cb = colBase & 1023;
            half_t* const vTp = (half_t*)C3 + bb * (1024LL * 2048) + tb;
            #pragma unroll
            for (int p = 0; p < 8; ++p) {
                const int idx = p * 256 + tid;
                const int cl  = idx >> 4;                // 0..127
                const int tc  = idx & 15;                // t-chunk
                half8 hv = *(const half8*)&smem[cl * 128 + 8 * (tc ^ (cl & 15))];
                *(half8*)(vTp + (long long)(cb + cl) * 2048 + tc * 8) = hv;
            }
        }
    }
}

// ---------------------------------------------------------------------------
// Kernel B (R10): fp16 NT GEMM, 256x256 tile, BK=64, 512 thr (8 waves,
// 2Mx4N of 128x64), 128 KB LDS double buffer, ONE vmcnt(0)+barrier per
// K-tile, ping-pong register A-slices. Used for S only (512 blocks = 2/CU).
// EPI: 0 = fp16 C store.
// ---------------------------------------------------------------------------
template<int EPI>
__global__ __launch_bounds__(512, 2)
void gemmB(const half_t* __restrict__ A, const half_t* __restrict__ B,
           void* __restrict__ Cv, void* __restrict__ C2, void* __restrict__ C3,
           const float* __restrict__ bias, int K, int lda, int ldb, int ldc,
           long long bsA, long long bsB, long long bsC)
{
    __shared__ half_t As[2 * 2 * 128 * 64];
    __shared__ half_t Bs[2 * 2 * 128 * 64];

    const int tid  = threadIdx.x;
    const int lane = tid & 63;
    const int w    = tid >> 6;           // 0..7
    const int wm   = w >> 2;             // 0..1 : wave row (128 C-rows)
    const int wn   = w & 3;              // 0..3 : wave col (64 C-cols)

    int bx = blockIdx.x, by = blockIdx.y, bz = blockIdx.z;
    {
        const int gx = gridDim.x, gy = gridDim.y;
        const int nwg = gx * gy * (int)gridDim.z;
        int lid = (bz * gy + by) * gx + bx;
        const int qq = nwg >> 3, rr = nwg & 7;
        const int xcd = lid & 7, off = lid >> 3;
        lid = (xcd < rr ? xcd * (qq + 1) : rr * (qq + 1) + (xcd - rr) * qq) + off;
        bx = lid % gx; lid /= gx;
        by = lid % gy; bz = lid / gy;
    }
    const long long z = bz;
    const int rowBase = by * 256;
    const int colBase = bx * 256;

    const int srow = lane >> 3;                 // 0..7
    const int schk = (lane & 7) ^ srow;
    const half_t* gp[4];
    int jstep[4];
    half_t* lp[4];
    #pragma unroll
    for (int i = 0; i < 4; ++i) {
        const bool ia = (i < 2);
        const int ld  = ia ? lda : ldb;
        const int rb  = (ia ? rowBase : colBase) + (i & 1) * 128 + w * 16 + srow;
        gp[i] = (ia ? A + z * bsA : B + z * bsB) + (long long)rb * ld + schk * 8;
        jstep[i] = 8 * ld;
        lp[i] = (ia ? As : Bs) + (i & 1) * 8192 + w * 1024;
    }

    const int fr  = lane & 15;
    const int q   = lane >> 4;
    const int rsw = fr & 7;
    const half_t* Abase = As + wm * 8192 + fr * 64;
    const half_t* Bbase = Bs + (wn >> 1) * 8192 + ((wn & 1) * 64 + fr) * 64;
    const int ko0 = ((0 + q) ^ rsw) * 8;
    const int ko1 = ((4 + q) ^ rsw) * 8;

    floatx4 acc[8][4];
    #pragma unroll
    for (int m = 0; m < 8; ++m)
        #pragma unroll
        for (int n = 0; n < 4; ++n)
            #pragma unroll
            for (int j = 0; j < 4; ++j) acc[m][n][j] = 0.0f;

    const int nIter = K >> 6;

    #pragma unroll
    for (int i = 0; i < 4; ++i) {
        GLD16(gp[i],            lp[i]);
        GLD16(gp[i] + jstep[i], lp[i] + 512);
    }
    WAIT_VM0();
    BARRIER();

    for (int t = 0; t < nIter; ++t) {
        const int cbuf = (t & 1) << 14;
        const int nbuf = 16384 - cbuf;
        half8 bf[4][2], afA[2][2], afB[2][2];

        #pragma unroll
        for (int n = 0; n < 4; ++n) {
            bf[n][0] = *(const half8*)(Bbase + cbuf + n * 1024 + ko0);
            bf[n][1] = *(const half8*)(Bbase + cbuf + n * 1024 + ko1);
        }
        afA[0][0] = *(const half8*)(Abase + cbuf + 0 * 1024 + ko0);
        afA[0][1] = *(const half8*)(Abase + cbuf + 0 * 1024 + ko1);
        afA[1][0] = *(const half8*)(Abase + cbuf + 1 * 1024 + ko0);
        afA[1][1] = *(const half8*)(Abase + cbuf + 1 * 1024 + ko1);

        if (t + 1 < nIter) {
            const int kk = (t + 1) << 6;
            #pragma unroll
            for (int i = 0; i < 4; ++i) {
                GLD16(gp[i] + kk,            lp[i] + nbuf);
                GLD16(gp[i] + kk + jstep[i], lp[i] + nbuf + 512);
            }
        }

        afB[0][0] = *(const half8*)(Abase + cbuf + 2 * 1024 + ko0);
        afB[0][1] = *(const half8*)(Abase + cbuf + 2 * 1024 + ko1);
        afB[1][0] = *(const half8*)(Abase + cbuf + 3 * 1024 + ko0);
        afB[1][1] = *(const half8*)(Abase + cbuf + 3 * 1024 + ko1);

        __builtin_amdgcn_s_setprio(1);
        #pragma unroll
        for (int ml = 0; ml < 2; ++ml)
            #pragma unroll
            for (int n = 0; n < 4; ++n)
                #pragma unroll
                for (int ks = 0; ks < 2; ++ks)
                    acc[ml][n] = __builtin_amdgcn_mfma_f32_16x16x32_f16(
                        afA[ml][ks], bf[n][ks], acc[ml][n], 0, 0, 0);
        __builtin_amdgcn_s_setprio(0);

        afA[0][0] = *(const half8*)(Abase + cbuf + 4 * 1024 + ko0);
        afA[0][1] = *(const half8*)(Abase + cbuf + 4 * 1024 + ko1);
        afA[1][0] = *(const half8*)(Abase + cbuf + 5 * 1024 + ko0);
        afA[1][1] = *(const half8*)(Abase + cbuf + 5 * 1024 + ko1);
        __builtin_amdgcn_s_setprio(1);
        #pragma unroll
        for (int ml = 0; ml < 2; ++ml)
            #pragma unroll
            for (int n = 0; n < 4; ++n)
                #pragma unroll
                for (int ks = 0; ks < 2; ++ks)
                    acc[2 + ml][n] = __builtin_amdgcn_mfma_f32_16x16x32_f16(
                        afB[ml][ks], bf[n][ks], acc[2 + ml][n], 0, 0, 0);
        __builtin_amdgcn_s_setprio(0);

        afB[0][0] = *(const half8*)(Abase + cbuf + 6 * 1024 + ko0);
        afB[0][1] = *(const half8*)(Abase + cbuf + 6 * 1024 + ko1);
        afB[1][0] = *(const half8*)(Abase + cbuf + 7 * 1024 + ko0);
        afB[1][1] = *(const half8*)(Abase + cbuf + 7 * 1024 + ko1);
        __builtin_amdgcn_s_setprio(1);
        #pragma unroll
        for (int ml = 0; ml < 2; ++ml)
            #pragma unroll
            for (int n = 0; n < 4; ++n)
                #pragma unroll
                for (int ks = 0; ks < 2; ++ks)
                    acc[4 + ml][n] = __builtin_amdgcn_mfma_f32_16x16x32_f16(
                        afA[ml][ks], bf[n][ks], acc[4 + ml][n], 0, 0, 0);
        __builtin_amdgcn_s_setprio(0);

        __builtin_amdgcn_s_setprio(1);
        #pragma unroll
        for (int ml = 0; ml < 2; ++ml)
            #pragma unroll
            for (int n = 0; n < 4; ++n)
                #pragma unroll
                for (int ks = 0; ks < 2; ++ks)
                    acc[6 + ml][n] = __builtin_amdgcn_mfma_f32_16x16x32_f16(
                        afB[ml][ks], bf[n][ks], acc[6 + ml][n], 0, 0, 0);
        __builtin_amdgcn_s_setprio(0);

        WAIT_VM0();
        BARRIER();
    }

    const int ecol = lane & 15;
    const int q4   = (lane >> 4) * 4;
    #pragma unroll
    for (int m = 0; m < 8; ++m)
        #pragma unroll
        for (int n = 0; n < 4; ++n) {
            const int gcol = colBase + wn * 64 + n * 16 + ecol;
            #pragma unroll
            for (int r = 0; r < 4; ++r) {
                const int grow = rowBase + wm * 128 + m * 16 + q4 + r;
                const float v = acc[m][n][r];
                if (EPI == 0) {
                    ((half_t*)Cv)[z * bsC + (long long)grow * ldc + gcol] = (half_t)v;
                } else {
                    ((float*)Cv)[(long long)grow * ldc + gcol] = v + bias[gcol];
                }
            }
        }
}

// fp32 -> fp16 flat cast, 8 elems/thread
__global__ __launch_bounds__(256)
void cast16(const float* __restrict__ x, half_t* __restrict__ y)
{
    const long long i = ((long long)blockIdx.x * 256 + threadIdx.x) * 8;
    floatx4 a = *(const floatx4*)(x + i);
    floatx4 b = *(const floatx4*)(x + i + 4);
    half8 h;
    #pragma unroll
    for (int j = 0; j < 4; ++j) { h[j] = (half_t)a[j]; h[j + 4] = (half_t)b[j]; }
    *(half8*)(y + i) = h;
}

// 1024x1024 fp32 -> fp16 transposed; grid.z selects which weight
__global__ __launch_bounds__(256)
void cast_transpose4(const float* __restrict__ W0, const float* __restrict__ W1,
                     const float* __restrict__ W2, const float* __restrict__ W3,
                     half_t* __restrict__ WT)
{
    const float* W = (blockIdx.z == 0) ? W0 : (blockIdx.z == 1) ? W1
                   : (blockIdx.z == 2) ? W2 : W3;
    half_t* O = WT + (long long)blockIdx.z * 1024 * 1024;
    __shared__ float t[32][33];
    const int bx = blockIdx.x * 32, by = blockIdx.y * 32;
    const int tx = threadIdx.x, ty = threadIdx.y;
    #pragma unroll
    for (int i = 0; i < 32; i += 8)
        t[ty + i][tx] = W[(long long)(by + ty + i) * 1024 + bx + tx];
    __syncthreads();
    #pragma unroll
    for (int i = 0; i < 32; i += 8)
        O[(long long)(bx + ty + i) * 1024 + by + tx] = (half_t)t[tx][ty + i];
}

// in-place fp16 row softmax over 2048; one 256-thr block per row; half8 I/O
__global__ __launch_bounds__(256)
void softmax_rows(half_t* __restrict__ S)
{
    const long long base = (long long)blockIdx.x * 2048;
    const int t = threadIdx.x;
    half8 h = *(const half8*)(S + base + t * 8);
    float v[8];
    #pragma unroll
    for (int i = 0; i < 8; ++i) v[i] = (float)h[i];
    float m = -3.0e38f;
    #pragma unroll
    for (int i = 0; i < 8; ++i) m = fmaxf(m, v[i]);
    #pragma unroll
    for (int off = 32; off > 0; off >>= 1) m = fmaxf(m, __shfl_down(m, off));
    __shared__ float redm[4], reds[4];
    const int lane = t & 63, wid = t >> 6;
    if (lane == 0) redm[wid] = m;
    __syncthreads();
    const float M = fmaxf(fmaxf(redm[0], redm[1]), fmaxf(redm[2], redm[3]));
    float s = 0.f;
    #pragma unroll
    for (int i = 0; i < 8; ++i) { v[i] = __expf(v[i] - M); s += v[i]; }
    #pragma unroll
    for (int off = 32; off > 0; off >>= 1) s += __shfl_down(s, off);
    if (lane == 0) reds[wid] = s;
    __syncthreads();
    const float inv = 1.0f / (reds[0] + reds[1] + reds[2] + reds[3]);
    #pragma unroll
    for (int i = 0; i < 8; ++i) h[i] = (half_t)(v[i] * inv);
    *(half8*)(S + base + t * 8) = h;
}

extern "C" void kernel_launch(void* const* d_in, const int* in_sizes, int n_in,
                              void* d_out, int out_size, void* d_ws, size_t ws_size,
                              hipStream_t stream)
{
    const float* x  = (const float*)d_in[0];
    const float* Wq = (const float*)d_in[1];
    const float* Wk = (const float*)d_in[2];
    const float* Wv = (const float*)d_in[3];
    const float* Wp = (const float*)d_in[4];
    const float* bp = (const float*)d_in[5];
    float* out = (float*)d_out;

    char* ws = (char*)d_ws;
    const long long MB = 1024LL * 1024LL;
    half_t* WqkvT = (half_t*)(ws + 0 * MB);   // [3072][1024] = WqT|WkT|WvT
    half_t* WpT   = (half_t*)(ws + 6 * MB);
    half_t* q     = (half_t*)(ws + 8 * MB);   // [8][2048][1024]; later ctx
    half_t* k     = (half_t*)(ws + 40 * MB);
    half_t* vT    = (half_t*)(ws + 72 * MB);  // [8][1024][2048]
    half_t* x16   = (half_t*)(ws + 104 * MB); // dead after QKV
    half_t* S     = (half_t*)(ws + 104 * MB); // [8][2048][2048] fp16, overlays x16

    cast16<<<8192, dim3(256), 0, stream>>>(x, x16);
    cast_transpose4<<<dim3(32, 32, 4), dim3(32, 8), 0, stream>>>(Wq, Wk, Wv, Wp, WqkvT);

    // fused QKV: [16384,1024] @ [3072,1024]^T, routed epilogue.
    // 128^2 kernel: 3072 blocks (4/CU).
    gemmA<2><<<dim3(24, 128, 1), dim3(256), 0, stream>>>(
        x16, WqkvT, q, k, vT, nullptr, 1024, 1024, 1024, 0, 0, 0, 0);

    // S = q @ k^T (fp16 out), all 8 batches. 256^2 kernel: 512 blocks (2/CU).
    gemmB<0><<<dim3(8, 8, 8), dim3(512), 0, stream>>>(
        q, k, S, nullptr, nullptr, nullptr, 1024, 1024, 1024, 2048,
        2048LL * 1024, 2048LL * 1024, 2048LL * 2048);

    // P = softmax(S) in place
    softmax_rows<<<8 * 2048, dim3(256), 0, stream>>>(S);

    // ctx = P @ vT^T (fp16), overwrites q. 128^2 kernel: 1024 blocks (4/CU).
    gemmA<0><<<dim3(8, 16, 8), dim3(256), 0, stream>>>(
        S, vT, q, nullptr, nullptr, nullptr, 2048, 2048, 2048, 1024,
        2048LL * 2048, 1024LL * 2048, 2048LL * 1024);

    // out = ctx @ WpT^T + bp (fp32). 128^2 kernel: 1024 blocks (4/CU).
    gemmA<1><<<dim3(8, 128, 1), dim3(256), 0, stream>>>(
        q, WpT, out, nullptr, nullptr, bp, 1024, 1024, 1024, 1024, 0, 0, 0);
}

// Round 9
// 457.818 us; speedup vs baseline: 1.0649x; 1.0649x over previous
//
#include <hip/hip_runtime.h>

// MiniSelfAttention: B=8, T=2048, D=1024, fp32 in/out, fp16 MFMA internally.
// R16 = R15 resubmitted verbatim (R15's bench was an infra failure: container
// acquire died twice; no kernel verdict). R15 = R13 (best measured, 460us)
// + wave-per-row softmax.
//  - R14's ctx/proj->gemmA move REGRESSED (+27us): ctx's A=S (64MB) is not
//    L2-resident, so the 128^2 tile's doubled panel re-reads beat the
//    co-residency gain. Tile choice follows operand residency. Reverted.
//  - softmax: one WAVE per row (4 rows/block), pure shfl_xor reductions,
//    zero __syncthreads / LDS. Old: 2 block barriers + LDS per row.
// Config: QKV on gemmA (128^2/BK=32, 4 blk/CU, LDS-transposed vT store);
// S, ctx, proj on gemmB (256^2/BK=64, 1 barrier/K-tile).
//
// ws layout (MB):
//   [0,6)    WqkvT = WqT|WkT|WvT contiguous (fp16 [3072][1024])
//   [6,8)    WpT fp16
//   [8,40)   q fp16 [8][2048][1024]   (later overwritten by ctx)
//   [40,72)  k fp16
//   [72,104) vT fp16 [8][1024][2048]
//   [104,136) x16 fp16 (dead after QKV), overlaid by:
//   [104,168) S fp16 [8][2048][2048]  (softmaxed in place -> P)

typedef _Float16 half_t;
typedef _Float16 half4 __attribute__((ext_vector_type(4)));
typedef _Float16 half8 __attribute__((ext_vector_type(8)));
typedef float floatx4 __attribute__((ext_vector_type(4)));

// async global->LDS, 16B per lane; LDS dest = wave-uniform base + lane*16
#define GLD16(gp, lp)                                                          \
    __builtin_amdgcn_global_load_lds(                                          \
        (const __attribute__((address_space(1))) void*)(gp),                   \
        (__attribute__((address_space(3))) void*)(lp), 16, 0, 0)

#define WAIT_VM0()  asm volatile("s_waitcnt vmcnt(0)" ::: "memory")
#define BARRIER()   do { asm volatile("" ::: "memory");                        \
                         __builtin_amdgcn_s_barrier();                         \
                         asm volatile("" ::: "memory"); } while (0)

// ---------------------------------------------------------------------------
// Kernel A: fp16 NT GEMM, 128x128 tile, BK=32, 256 thr (4 waves 64x64),
// 32 KB double-buffered LDS (4 blocks/CU), XOR-swizzled chunks.
// QKV routed epilogue only: q*1/32, k row-major, vT via LDS-transpose.
// ---------------------------------------------------------------------------
template<int EPI>
__global__ __launch_bounds__(256, 4)
void gemmA(const half_t* __restrict__ A, const half_t* __restrict__ B,
           void* __restrict__ Cv, void* __restrict__ C2, void* __restrict__ C3,
           const float* __restrict__ bias, int K, int lda, int ldb, int ldc,
           long long bsA, long long bsB, long long bsC)
{
    __shared__ half_t smem[16384];       // 32 KB: As(16KB) | Bs(16KB)
    half_t* const As = smem;             // reused whole as vt[128][128] in epi
    half_t* const Bs = smem + 8192;

    const int tid  = threadIdx.x;
    const int lane = tid & 63;
    const int w    = tid >> 6;           // 0..3
    const int wm   = w >> 1;             // wave grid 2 (rows) x 2 (cols)
    const int wn   = w & 1;

    // bijective XCD remap (m204) of flattened block id
    int bx = blockIdx.x, by = blockIdx.y, bz = blockIdx.z;
    {
        const int gx = gridDim.x, gy = gridDim.y;
        const int nwg = gx * gy * (int)gridDim.z;
        int lid = (bz * gy + by) * gx + bx;
        const int qq = nwg >> 3, rr = nwg & 7;
        const int xcd = lid & 7, off = lid >> 3;
        lid = (xcd < rr ? xcd * (qq + 1) : rr * (qq + 1) + (xcd - rr) * qq) + off;
        bx = lid % gx; lid /= gx;
        by = lid % gy; bz = lid / gy;
    }
    const long long z = bz;
    const int rowBase = by * 128;
    const int colBase = bx * 128;

    // staging: 256 rows of 64B = 16 groups of 16 rows, 4 groups per wave.
    // SWIZZLE: lane stages global chunk (lane&3)^((lane>>3)&3) of its row,
    // so LDS slot (r, sc) holds global chunk sc^((r>>1)&3).
    const int lrow = lane >> 2;                              // 0..15
    const int scol = (((lane & 3) ^ ((lane >> 3) & 3))) * 8; // swizzled chunk

    const half_t* gptr[4];
    int  lofs[4];
    bool isA[4];
    #pragma unroll
    for (int j = 0; j < 4; ++j) {
        const int g = w * 4 + j;          // 0..15
        if (g < 8) {
            gptr[j] = A + z * bsA + (long long)(rowBase + g * 16 + lrow) * lda + scol;
            lofs[j] = g * 16 * 32;
            isA[j]  = true;
        } else {
            gptr[j] = B + z * bsB + (long long)(colBase + (g - 8) * 16 + lrow) * ldb + scol;
            lofs[j] = (g - 8) * 16 * 32;
            isA[j]  = false;
        }
    }

    floatx4 acc[4][4];
    #pragma unroll
    for (int m = 0; m < 4; ++m)
        #pragma unroll
        for (int n = 0; n < 4; ++n)
            #pragma unroll
            for (int j = 0; j < 4; ++j) acc[m][n][j] = 0.0f;

    const int fr  = lane & 15;
    const int fks = (((lane >> 4) ^ ((lane >> 1) & 3))) * 8;
    const int nIter = K >> 5;

    #pragma unroll
    for (int j = 0; j < 4; ++j)
        GLD16(gptr[j], isA[j] ? &As[lofs[j]] : &Bs[lofs[j]]);
    WAIT_VM0();
    BARRIER();

    for (int it = 0; it < nIter; ++it) {
        const int cur = (it & 1) * 4096;
        const int nxt = 4096 - cur;
        if (it + 1 < nIter) {
            const int kk = (it + 1) << 5;
            #pragma unroll
            for (int j = 0; j < 4; ++j)
                GLD16(gptr[j] + kk, isA[j] ? &As[nxt + lofs[j]] : &Bs[nxt + lofs[j]]);
        }

        half8 af[4], bf[4];
        #pragma unroll
        for (int m = 0; m < 4; ++m)
            af[m] = *(const half8*)&As[cur + (wm * 64 + m * 16 + fr) * 32 + fks];
        #pragma unroll
        for (int n = 0; n < 4; ++n)
            bf[n] = *(const half8*)&Bs[cur + (wn * 64 + n * 16 + fr) * 32 + fks];
        #pragma unroll
        for (int m = 0; m < 4; ++m)
            #pragma unroll
            for (int n = 0; n < 4; ++n)
                acc[m][n] = __builtin_amdgcn_mfma_f32_16x16x32_f16(af[m], bf[n], acc[m][n], 0, 0, 0);

        WAIT_VM0();
        BARRIER();
    }

    // epilogue: C/D layout col=lane&15, row=(lane>>4)*4+reg (gfx950-verified)
    // All routing branches are BLOCK-UNIFORM (computed from colBase).
    const int ecol = lane & 15;
    const int q4   = (lane >> 4) * 4;
    const int mat  = colBase >> 10;      // 0=q, 1=k, 2=v (uniform)
    if (mat < 2) {
        half_t* const Cq = (mat == 0) ? (half_t*)Cv : (half_t*)C2;
        const float sc = (mat == 0) ? 0.03125f : 1.0f;
        const int cb = colBase & 1023;
        #pragma unroll
        for (int m = 0; m < 4; ++m)
            #pragma unroll
            for (int n = 0; n < 4; ++n) {
                const int c = cb + wn * 64 + n * 16 + ecol;
                #pragma unroll
                for (int r = 0; r < 4; ++r) {
                    const int grow = rowBase + wm * 64 + m * 16 + q4 + r;
                    Cq[(long long)grow * 1024 + c] = (half_t)(acc[m][n][r] * sc);
                }
            }
    } else {
        // vT[b][c][t] via LDS transpose. smem (32 KB) is dead after the
        // K-loop's final barrier. Layout: vt[c][t] with chunk-XOR swizzle:
        // halves addr = c*128 + 8*((t>>3)^(c&15)) + (t&7). q4+r spans 4
        // consecutive t within one 8-chunk -> half4 writes, 8B aligned.
        #pragma unroll
        for (int m = 0; m < 4; ++m) {
            const int t0  = wm * 64 + m * 16 + q4;   // 4-aligned
            const int tch = t0 >> 3, tof = t0 & 7;
            #pragma unroll
            for (int n = 0; n < 4; ++n) {
                const int cl = wn * 64 + n * 16 + ecol;
                half4 hv;
                #pragma unroll
                for (int r = 0; r < 4; ++r) hv[r] = (half_t)acc[m][n][r];
                *(half4*)&smem[cl * 128 + 8 * (tch ^ (cl & 15)) + tof] = hv;
            }
        }
        BARRIER();
        // stream out: 2048 half8 chunks; lane-consecutive t-chunks within a
        // c-row -> fully coalesced 16B stores.
        const long long bb = rowBase >> 11;          // batch (block-uniform)
        const int tb = rowBase & 2047;
        const int cb = colBase & 1023;
        half_t* const vTp = (half_t*)C3 + bb * (1024LL * 2048) + tb;
        #pragma unroll
        for (int p = 0; p < 8; ++p) {
            const int idx = p * 256 + tid;
            const int cl  = idx >> 4;                // 0..127
            const int tc  = idx & 15;                // t-chunk
            half8 hv = *(const half8*)&smem[cl * 128 + 8 * (tc ^ (cl & 15))];
            *(half8*)(vTp + (long long)(cb + cl) * 2048 + tc * 8) = hv;
        }
    }
}

// ---------------------------------------------------------------------------
// Kernel B (R10): fp16 NT GEMM, 256x256 tile, BK=64, 512 thr (8 waves,
// 2Mx4N of 128x64), 128 KB LDS double buffer, ONE vmcnt(0)+barrier per
// K-tile, ping-pong register A-slices. Used for S, ctx, proj.
// EPI: 0 = fp16 C store; 1 = fp32 C + bias.
// ---------------------------------------------------------------------------
template<int EPI>
__global__ __launch_bounds__(512, 2)
void gemmB(const half_t* __restrict__ A, const half_t* __restrict__ B,
           void* __restrict__ Cv, void* __restrict__ C2, void* __restrict__ C3,
           const float* __restrict__ bias, int K, int lda, int ldb, int ldc,
           long long bsA, long long bsB, long long bsC)
{
    __shared__ half_t As[2 * 2 * 128 * 64];
    __shared__ half_t Bs[2 * 2 * 128 * 64];

    const int tid  = threadIdx.x;
    const int lane = tid & 63;
    const int w    = tid >> 6;           // 0..7
    const int wm   = w >> 2;             // 0..1 : wave row (128 C-rows)
    const int wn   = w & 3;              // 0..3 : wave col (64 C-cols)

    int bx = blockIdx.x, by = blockIdx.y, bz = blockIdx.z;
    {
        const int gx = gridDim.x, gy = gridDim.y;
        const int nwg = gx * gy * (int)gridDim.z;
        int lid = (bz * gy + by) * gx + bx;
        const int qq = nwg >> 3, rr = nwg & 7;
        const int xcd = lid & 7, off = lid >> 3;
        lid = (xcd < rr ? xcd * (qq + 1) : rr * (qq + 1) + (xcd - rr) * qq) + off;
        bx = lid % gx; lid /= gx;
        by = lid % gy; bz = lid / gy;
    }
    const long long z = bz;
    const int rowBase = by * 256;
    const int colBase = bx * 256;

    const int srow = lane >> 3;                 // 0..7
    const int schk = (lane & 7) ^ srow;
    const half_t* gp[4];
    int jstep[4];
    half_t* lp[4];
    #pragma unroll
    for (int i = 0; i < 4; ++i) {
        const bool ia = (i < 2);
        const int ld  = ia ? lda : ldb;
        const int rb  = (ia ? rowBase : colBase) + (i & 1) * 128 + w * 16 + srow;
        gp[i] = (ia ? A + z * bsA : B + z * bsB) + (long long)rb * ld + schk * 8;
        jstep[i] = 8 * ld;
        lp[i] = (ia ? As : Bs) + (i & 1) * 8192 + w * 1024;
    }

    const int fr  = lane & 15;
    const int q   = lane >> 4;
    const int rsw = fr & 7;
    const half_t* Abase = As + wm * 8192 + fr * 64;
    const half_t* Bbase = Bs + (wn >> 1) * 8192 + ((wn & 1) * 64 + fr) * 64;
    const int ko0 = ((0 + q) ^ rsw) * 8;
    const int ko1 = ((4 + q) ^ rsw) * 8;

    floatx4 acc[8][4];
    #pragma unroll
    for (int m = 0; m < 8; ++m)
        #pragma unroll
        for (int n = 0; n < 4; ++n)
            #pragma unroll
            for (int j = 0; j < 4; ++j) acc[m][n][j] = 0.0f;

    const int nIter = K >> 6;

    #pragma unroll
    for (int i = 0; i < 4; ++i) {
        GLD16(gp[i],            lp[i]);
        GLD16(gp[i] + jstep[i], lp[i] + 512);
    }
    WAIT_VM0();
    BARRIER();

    for (int t = 0; t < nIter; ++t) {
        const int cbuf = (t & 1) << 14;
        const int nbuf = 16384 - cbuf;
        half8 bf[4][2], afA[2][2], afB[2][2];

        #pragma unroll
        for (int n = 0; n < 4; ++n) {
            bf[n][0] = *(const half8*)(Bbase + cbuf + n * 1024 + ko0);
            bf[n][1] = *(const half8*)(Bbase + cbuf + n * 1024 + ko1);
        }
        afA[0][0] = *(const half8*)(Abase + cbuf + 0 * 1024 + ko0);
        afA[0][1] = *(const half8*)(Abase + cbuf + 0 * 1024 + ko1);
        afA[1][0] = *(const half8*)(Abase + cbuf + 1 * 1024 + ko0);
        afA[1][1] = *(const half8*)(Abase + cbuf + 1 * 1024 + ko1);

        if (t + 1 < nIter) {
            const int kk = (t + 1) << 6;
            #pragma unroll
            for (int i = 0; i < 4; ++i) {
                GLD16(gp[i] + kk,            lp[i] + nbuf);
                GLD16(gp[i] + kk + jstep[i], lp[i] + nbuf + 512);
            }
        }

        afB[0][0] = *(const half8*)(Abase + cbuf + 2 * 1024 + ko0);
        afB[0][1] = *(const half8*)(Abase + cbuf + 2 * 1024 + ko1);
        afB[1][0] = *(const half8*)(Abase + cbuf + 3 * 1024 + ko0);
        afB[1][1] = *(const half8*)(Abase + cbuf + 3 * 1024 + ko1);

        __builtin_amdgcn_s_setprio(1);
        #pragma unroll
        for (int ml = 0; ml < 2; ++ml)
            #pragma unroll
            for (int n = 0; n < 4; ++n)
                #pragma unroll
                for (int ks = 0; ks < 2; ++ks)
                    acc[ml][n] = __builtin_amdgcn_mfma_f32_16x16x32_f16(
                        afA[ml][ks], bf[n][ks], acc[ml][n], 0, 0, 0);
        __builtin_amdgcn_s_setprio(0);

        afA[0][0] = *(const half8*)(Abase + cbuf + 4 * 1024 + ko0);
        afA[0][1] = *(const half8*)(Abase + cbuf + 4 * 1024 + ko1);
        afA[1][0] = *(const half8*)(Abase + cbuf + 5 * 1024 + ko0);
        afA[1][1] = *(const half8*)(Abase + cbuf + 5 * 1024 + ko1);
        __builtin_amdgcn_s_setprio(1);
        #pragma unroll
        for (int ml = 0; ml < 2; ++ml)
            #pragma unroll
            for (int n = 0; n < 4; ++n)
                #pragma unroll
                for (int ks = 0; ks < 2; ++ks)
                    acc[2 + ml][n] = __builtin_amdgcn_mfma_f32_16x16x32_f16(
                        afB[ml][ks], bf[n][ks], acc[2 + ml][n], 0, 0, 0);
        __builtin_amdgcn_s_setprio(0);

        afB[0][0] = *(const half8*)(Abase + cbuf + 6 * 1024 + ko0);
        afB[0][1] = *(const half8*)(Abase + cbuf + 6 * 1024 + ko1);
        afB[1][0] = *(const half8*)(Abase + cbuf + 7 * 1024 + ko0);
        afB[1][1] = *(const half8*)(Abase + cbuf + 7 * 1024 + ko1);
        __builtin_amdgcn_s_setprio(1);
        #pragma unroll
        for (int ml = 0; ml < 2; ++ml)
            #pragma unroll
            for (int n = 0; n < 4; ++n)
                #pragma unroll
                for (int ks = 0; ks < 2; ++ks)
                    acc[4 + ml][n] = __builtin_amdgcn_mfma_f32_16x16x32_f16(
                        afA[ml][ks], bf[n][ks], acc[4 + ml][n], 0, 0, 0);
        __builtin_amdgcn_s_setprio(0);

        __builtin_amdgcn_s_setprio(1);
        #pragma unroll
        for (int ml = 0; ml < 2; ++ml)
            #pragma unroll
            for (int n = 0; n < 4; ++n)
                #pragma unroll
                for (int ks = 0; ks < 2; ++ks)
                    acc[6 + ml][n] = __builtin_amdgcn_mfma_f32_16x16x32_f16(
                        afB[ml][ks], bf[n][ks], acc[6 + ml][n], 0, 0, 0);
        __builtin_amdgcn_s_setprio(0);

        WAIT_VM0();
        BARRIER();
    }

    const int ecol = lane & 15;
    const int q4   = (lane >> 4) * 4;
    #pragma unroll
    for (int m = 0; m < 8; ++m)
        #pragma unroll
        for (int n = 0; n < 4; ++n) {
            const int gcol = colBase + wn * 64 + n * 16 + ecol;
            #pragma unroll
            for (int r = 0; r < 4; ++r) {
                const int grow = rowBase + wm * 128 + m * 16 + q4 + r;
                const float v = acc[m][n][r];
                if (EPI == 0) {
                    ((half_t*)Cv)[z * bsC + (long long)grow * ldc + gcol] = (half_t)v;
                } else {
                    ((float*)Cv)[(long long)grow * ldc + gcol] = v + bias[gcol];
                }
            }
        }
}

// fp32 -> fp16 flat cast, 8 elems/thread
__global__ __launch_bounds__(256)
void cast16(const float* __restrict__ x, half_t* __restrict__ y)
{
    const long long i = ((long long)blockIdx.x * 256 + threadIdx.x) * 8;
    floatx4 a = *(const floatx4*)(x + i);
    floatx4 b = *(const floatx4*)(x + i + 4);
    half8 h;
    #pragma unroll
    for (int j = 0; j < 4; ++j) { h[j] = (half_t)a[j]; h[j + 4] = (half_t)b[j]; }
    *(half8*)(y + i) = h;
}

// 1024x1024 fp32 -> fp16 transposed; grid.z selects which weight
__global__ __launch_bounds__(256)
void cast_transpose4(const float* __restrict__ W0, const float* __restrict__ W1,
                     const float* __restrict__ W2, const float* __restrict__ W3,
                     half_t* __restrict__ WT)
{
    const float* W = (blockIdx.z == 0) ? W0 : (blockIdx.z == 1) ? W1
                   : (blockIdx.z == 2) ? W2 : W3;
    half_t* O = WT + (long long)blockIdx.z * 1024 * 1024;
    __shared__ float t[32][33];
    const int bx = blockIdx.x * 32, by = blockIdx.y * 32;
    const int tx = threadIdx.x, ty = threadIdx.y;
    #pragma unroll
    for (int i = 0; i < 32; i += 8)
        t[ty + i][tx] = W[(long long)(by + ty + i) * 1024 + bx + tx];
    __syncthreads();
    #pragma unroll
    for (int i = 0; i < 32; i += 8)
        O[(long long)(bx + ty + i) * 1024 + by + tx] = (half_t)t[tx][ty + i];
}

// in-place fp16 row softmax over 2048; ONE WAVE per row (4 rows/block),
// pure shfl_xor reductions — no __syncthreads, no LDS.
__global__ __launch_bounds__(256)
void softmax_rows(half_t* __restrict__ S)
{
    const int lane = threadIdx.x & 63;
    const long long row = (long long)blockIdx.x * 4 + (threadIdx.x >> 6);
    half_t* const p = S + row * 2048 + lane * 8;

    // 4 chunks of half8, 512 elems apart: fully coalesced 16B/lane per chunk
    half8 h[4];
    #pragma unroll
    for (int c = 0; c < 4; ++c) h[c] = *(const half8*)(p + c * 512);

    float v[32];
    float m = -3.0e38f;
    #pragma unroll
    for (int c = 0; c < 4; ++c)
        #pragma unroll
        for (int i = 0; i < 8; ++i) {
            v[c * 8 + i] = (float)h[c][i];
            m = fmaxf(m, v[c * 8 + i]);
        }
    #pragma unroll
    for (int off = 32; off > 0; off >>= 1) m = fmaxf(m, __shfl_xor(m, off));

    float s = 0.f;
    #pragma unroll
    for (int i = 0; i < 32; ++i) { v[i] = __expf(v[i] - m); s += v[i]; }
    #pragma unroll
    for (int off = 32; off > 0; off >>= 1) s += __shfl_xor(s, off);

    const float inv = 1.0f / s;
    #pragma unroll
    for (int c = 0; c < 4; ++c) {
        #pragma unroll
        for (int i = 0; i < 8; ++i) h[c][i] = (half_t)(v[c * 8 + i] * inv);
        *(half8*)(p + c * 512) = h[c];
    }
}

extern "C" void kernel_launch(void* const* d_in, const int* in_sizes, int n_in,
                              void* d_out, int out_size, void* d_ws, size_t ws_size,
                              hipStream_t stream)
{
    const float* x  = (const float*)d_in[0];
    const float* Wq = (const float*)d_in[1];
    const float* Wk = (const float*)d_in[2];
    const float* Wv = (const float*)d_in[3];
    const float* Wp = (const float*)d_in[4];
    const float* bp = (const float*)d_in[5];
    float* out = (float*)d_out;

    char* ws = (char*)d_ws;
    const long long MB = 1024LL * 1024LL;
    half_t* WqkvT = (half_t*)(ws + 0 * MB);   // [3072][1024] = WqT|WkT|WvT
    half_t* WpT   = (half_t*)(ws + 6 * MB);
    half_t* q     = (half_t*)(ws + 8 * MB);   // [8][2048][1024]; later ctx
    half_t* k     = (half_t*)(ws + 40 * MB);
    half_t* vT    = (half_t*)(ws + 72 * MB);  // [8][1024][2048]
    half_t* x16   = (half_t*)(ws + 104 * MB); // dead after QKV
    half_t* S     = (half_t*)(ws + 104 * MB); // [8][2048][2048] fp16, overlays x16

    cast16<<<8192, dim3(256), 0, stream>>>(x, x16);
    cast_transpose4<<<dim3(32, 32, 4), dim3(32, 8), 0, stream>>>(Wq, Wk, Wv, Wp, WqkvT);

    // fused QKV: [16384,1024] @ [3072,1024]^T, routed epilogue.
    // 128^2 kernel: 3072 blocks (4/CU).
    gemmA<2><<<dim3(24, 128, 1), dim3(256), 0, stream>>>(
        x16, WqkvT, q, k, vT, nullptr, 1024, 1024, 1024, 0, 0, 0, 0);

    // S = q @ k^T (fp16 out), all 8 batches. 256^2 kernel: 512 blocks (2/CU).
    gemmB<0><<<dim3(8, 8, 8), dim3(512), 0, stream>>>(
        q, k, S, nullptr, nullptr, nullptr, 1024, 1024, 1024, 2048,
        2048LL * 1024, 2048LL * 1024, 2048LL * 2048);

    // P = softmax(S) in place: 16384 rows, 4 rows/block.
    softmax_rows<<<4096, dim3(256), 0, stream>>>(S);

    // ctx = P @ vT^T (fp16), overwrites q. 256^2 kernel: 256 blocks.
    gemmB<0><<<dim3(4, 8, 8), dim3(512), 0, stream>>>(
        S, vT, q, nullptr, nullptr, nullptr, 2048, 2048, 2048, 1024,
        2048LL * 2048, 1024LL * 2048, 2048LL * 1024);

    // out = ctx @ WpT^T + bp (fp32). 256^2 kernel: 256 blocks.
    gemmB<1><<<dim3(4, 64, 1), dim3(512), 0, stream>>>(
        q, WpT, out, nullptr, nullptr, bp, 1024, 1024, 1024, 1024, 0, 0, 0);
}